// Round 1
// 898.001 us; speedup vs baseline: 1.2063x; 1.2063x over previous
//
#include <hip/hip_runtime.h>
#include <stdint.h>
#include <stddef.h>

// Problem dims (fixed by reference)
#define M_DIM 16384   // 8*2048
#define K_DIM 4096
#define N_DIM 4096

// GEMM tiling: 256x256 tile, BK=64, 8 waves (2M x 4N), 8-phase schedule
#define BM 256
#define BN 256
#define BK 64

// Workspace layout
#define WS_SUM_OFF   0                    // double final |W| sum
#define WS_PART_OFF  256                  // 1024 double partials
#define WS_X_OFF     16384                // x as bf16: 16384*4096*2 = 134217728 B
#define WS_XBYTES    ((size_t)M_DIM * K_DIM * 2)
#define WS_W_OFF     (WS_X_OFF + WS_XBYTES)
#define WS_WBYTES    ((size_t)N_DIM * K_DIM * 2)
#define WS_NEEDED    (WS_W_OFF + WS_WBYTES)

typedef __attribute__((ext_vector_type(8))) short short8;   // 8 bf16 = 4 VGPRs
typedef __attribute__((ext_vector_type(4))) float floatx4;  // MFMA 16x16 accumulator

// float -> bf16 bits, round-to-nearest-even
__device__ __forceinline__ unsigned short f2bf_rne(float f) {
  unsigned u = __builtin_bit_cast(unsigned, f);
  u += 0x7FFFu + ((u >> 16) & 1u);
  return (unsigned short)(u >> 16);
}

__device__ __forceinline__ float get_scale(const double* __restrict__ sum) {
  double m = *sum * (1.0 / 16777216.0);
  return (float)fmax(m, 1e-8);
}

// async global->LDS, 16 B per lane; LDS dest is wave-uniform base + lane*16
__device__ __forceinline__ void gload16(const void* g, void* l) {
  __builtin_amdgcn_global_load_lds(
      (const __attribute__((address_space(1))) void*)g,
      (__attribute__((address_space(3))) void*)l,
      16, 0, 0);
}

// ---------------------------------------------------------------------------
// Kernel 1 (fused): blocks [0,1024): sum|W| -> double partials (deterministic)
//                   blocks [1024,4096): convert x fp32 -> bf16
// ---------------------------------------------------------------------------
__global__ void prep_kernel(const float* __restrict__ W, double* __restrict__ partials,
                            const float* __restrict__ X, unsigned short* __restrict__ XO) {
  if (blockIdx.x < 1024) {
    const int n4 = (N_DIM * K_DIM) / 4;  // 4194304 float4s
    const float4* W4 = (const float4*)W;
    float s = 0.f;
    const int stride = 1024 * blockDim.x;
    for (int i = blockIdx.x * blockDim.x + threadIdx.x; i < n4; i += stride) {
      float4 v = W4[i];
      s += fabsf(v.x) + fabsf(v.y) + fabsf(v.z) + fabsf(v.w);
    }
#pragma unroll
    for (int off = 32; off > 0; off >>= 1) s += __shfl_down(s, off);
    __shared__ double bsum[4];
    if ((threadIdx.x & 63) == 0) bsum[threadIdx.x >> 6] = (double)s;
    __syncthreads();
    if (threadIdx.x == 0)
      partials[blockIdx.x] = bsum[0] + bsum[1] + bsum[2] + bsum[3];
  } else {
    const int n4 = (M_DIM * K_DIM) / 4;  // 16777216 float4s
    const float4* X4 = (const float4*)X;
    ushort4* O4 = (ushort4*)XO;
    const int nblk = 3072;
    const int stride = nblk * blockDim.x;
    for (int i = (blockIdx.x - 1024) * blockDim.x + threadIdx.x; i < n4; i += stride) {
      float4 v = X4[i];
      ushort4 o;
      o.x = f2bf_rne(v.x); o.y = f2bf_rne(v.y); o.z = f2bf_rne(v.z); o.w = f2bf_rne(v.w);
      O4[i] = o;
    }
  }
}

// ---------------------------------------------------------------------------
// Kernel 2: reduce 1024 partials -> final double sum (deterministic)
// ---------------------------------------------------------------------------
__global__ void reduce2_kernel(const double* __restrict__ partials, double* __restrict__ sum) {
  double s = 0.0;
  for (int i = threadIdx.x; i < 1024; i += 256) s += partials[i];
#pragma unroll
  for (int off = 32; off > 0; off >>= 1) s += __shfl_down(s, off);
  __shared__ double wsum[4];
  if ((threadIdx.x & 63) == 0) wsum[threadIdx.x >> 6] = s;
  __syncthreads();
  if (threadIdx.x == 0) *sum = wsum[0] + wsum[1] + wsum[2] + wsum[3];
}

// ---------------------------------------------------------------------------
// Kernel 3: quantize W -> ternary {-1,0,1} stored as bf16 (exact in bf16)
// ---------------------------------------------------------------------------
__global__ void quantw_kernel(const float* __restrict__ W, const double* __restrict__ sum,
                              unsigned short* __restrict__ T) {
  const int n4 = (N_DIM * K_DIM) / 4;
  const float s = get_scale(sum);
  const float4* W4 = (const float4*)W;
  ushort4* T4 = (ushort4*)T;
  const int stride = gridDim.x * blockDim.x;
  for (int i = blockIdx.x * blockDim.x + threadIdx.x; i < n4; i += stride) {
    float4 v = W4[i];
    float q0 = fminf(fmaxf(rintf(v.x / s), -1.f), 1.f);
    float q1 = fminf(fmaxf(rintf(v.y / s), -1.f), 1.f);
    float q2 = fminf(fmaxf(rintf(v.z / s), -1.f), 1.f);
    float q3 = fminf(fmaxf(rintf(v.w / s), -1.f), 1.f);
    ushort4 o;
    o.x = f2bf_rne(q0); o.y = f2bf_rne(q1); o.z = f2bf_rne(q2); o.w = f2bf_rne(q3);
    T4[i] = o;
  }
}

// ---------------------------------------------------------------------------
// Kernel 4: GEMM  C[m,n] = s * sum_k A[m,k]*T[n,k] + bias[n]
//
// 256x256 tile, BK=64, 512 threads (8 waves: wm in {0,1} x wn in {0..3}),
// per-wave output 128x64 (acc[8][4] of 16x16 frags). Double-buffered LDS
// (128 KiB), raw s_barrier (no counter drain), counted vmcnt(6) so three
// 16 KiB half-tiles of global_load_lds prefetch stay in flight across
// barriers, s_setprio(1) around each 16-MFMA cluster.
//
// LDS bank swizzle: row stride is 128 B (exactly 32 banks), so unswizzled
// ds_read_b128 would 16-way-conflict. Physical 16B chunk p of row r holds
// global chunk p ^ (r&7): each 8-lane phase of a ds_read_b128 then covers
// all 32 banks (conflict-free; the BK=32 variant of this measured 0
// conflicts). global_load_lds writes linearly, so the source address is
// pre-swizzled with the same involution (both-sides-or-neither).
//
// Staging schedule (all writes >= 2 barriers after the last read of the
// target region; B frags are read ONCE per tile at q=0 into regs; q=3's A
// frags are prefetched at q=2 so the A1 half is dead when overwritten):
//   q=0: stage tile t+1 B1  (other buffer, idle)
//   q=1: stage tile t+2 B0  (B of this buffer dead after q=0)
//   q=2: stage tile t+2 A0  (rows 0-63,128-191: dead after q=1)
//   q=3: stage tile t+2 A1  (rows 64-127,192-255: dead after q=2 prefetch)
// vmcnt(6) at q=3 = 3 half-tiles x 2 loads in flight; the half needed next
// (t+1 B1) was issued 3.5 phases earlier -> latency hidden.
// ---------------------------------------------------------------------------
__device__ __forceinline__ void stage64(const unsigned short* __restrict__ src,
                                        int gRow0, int kBase, char* ldsSlab) {
  // One 64-row x 64-col bf16 slab (8 KiB): thread t covers LDS linear byte
  // t*16 -> row t>>3, physical chunk t&7; fetch global chunk (t&7)^(r&7).
  const int t = threadIdx.x;
  const int r = t >> 3;
  const int g = (t & 7) ^ (r & 7);
  gload16(src + (size_t)(gRow0 + r) * K_DIM + kBase + (g << 3),
          ldsSlab + ((t >> 6) << 10));   // wave-uniform base; HW adds lane*16
}

template <int Q>
__device__ __forceinline__ void mfma_quad(floatx4 (&acc)[8][4],
                                          const short8 (&F)[2][2],
                                          const short8 (&bfr)[4][2]) {
#pragma unroll
  for (int j = 0; j < 2; ++j) {
#pragma unroll
    for (int ni = 0; ni < 4; ++ni) {
      acc[2 * Q + j][ni] = __builtin_amdgcn_mfma_f32_16x16x32_bf16(
          F[j][0], bfr[ni][0], acc[2 * Q + j][ni], 0, 0, 0);
      acc[2 * Q + j][ni] = __builtin_amdgcn_mfma_f32_16x16x32_bf16(
          F[j][1], bfr[ni][1], acc[2 * Q + j][ni], 0, 0, 0);
    }
  }
}

#define LDA(P, off) (*(const short8*)(smem + (P) * 65536 + (off)))
#define LDB(P, off) (*(const short8*)(smem + (P) * 65536 + 32768 + (off)))

#define TILE_BODY(T, P)                                                       \
  {                                                                           \
    /* -- q=0: B frags (8 reads, held all tile) + A q0 frags (4 reads) -- */  \
    _Pragma("unroll")                                                         \
    for (int ni = 0; ni < 4; ++ni) {                                          \
      bf[ni][0] = LDB(P, bOff0 + ni * 2048);                                  \
      bf[ni][1] = LDB(P, bOff1 + ni * 2048);                                  \
    }                                                                         \
    afA[0][0] = LDA(P, aOff0);        afA[0][1] = LDA(P, aOff1);              \
    afA[1][0] = LDA(P, aOff0 + 2048); afA[1][1] = LDA(P, aOff1 + 2048);       \
    if ((T) + 1 < 64) {                                                       \
      stage64(B, blockN + 128, ((T) + 1) << 6,                                \
              smem + (1 - (P)) * 65536 + 32768 + 128 * 128);                  \
      stage64(B, blockN + 192, ((T) + 1) << 6,                                \
              smem + (1 - (P)) * 65536 + 32768 + 192 * 128);                  \
    }                                                                         \
    __builtin_amdgcn_s_barrier();                                             \
    asm volatile("s_waitcnt lgkmcnt(0)" ::: "memory");                        \
    __builtin_amdgcn_sched_barrier(0);                                        \
    __builtin_amdgcn_s_setprio(1);                                            \
    mfma_quad<0>(acc, afA, bf);                                               \
    __builtin_amdgcn_s_setprio(0);                                            \
    __builtin_amdgcn_s_barrier();                                             \
    /* -- q=1 -- */                                                           \
    afA[0][0] = LDA(P, aOff0 + 4096); afA[0][1] = LDA(P, aOff1 + 4096);       \
    afA[1][0] = LDA(P, aOff0 + 6144); afA[1][1] = LDA(P, aOff1 + 6144);       \
    if ((T) + 2 < 64) {                                                       \
      stage64(B, blockN + 0,  ((T) + 2) << 6, smem + (P) * 65536 + 32768);    \
      stage64(B, blockN + 64, ((T) + 2) << 6,                                 \
              smem + (P) * 65536 + 32768 + 64 * 128);                         \
    }                                                                         \
    __builtin_amdgcn_s_barrier();                                             \
    asm volatile("s_waitcnt lgkmcnt(0)" ::: "memory");                        \
    __builtin_amdgcn_sched_barrier(0);                                        \
    __builtin_amdgcn_s_setprio(1);                                            \
    mfma_quad<1>(acc, afA, bf);                                               \
    __builtin_amdgcn_s_setprio(0);                                            \
    __builtin_amdgcn_s_barrier();                                             \
    /* -- q=2: also prefetch q=3's A frags so A1 is dead at q=3 -- */         \
    afA[0][0] = LDA(P, aOff0 + 8192);  afA[0][1] = LDA(P, aOff1 + 8192);      \
    afA[1][0] = LDA(P, aOff0 + 10240); afA[1][1] = LDA(P, aOff1 + 10240);     \
    afB[0][0] = LDA(P, aOff0 + 12288); afB[0][1] = LDA(P, aOff1 + 12288);     \
    afB[1][0] = LDA(P, aOff0 + 14336); afB[1][1] = LDA(P, aOff1 + 14336);     \
    if ((T) + 2 < 64) {                                                       \
      stage64(A, blockM + 0,   ((T) + 2) << 6, smem + (P) * 65536);           \
      stage64(A, blockM + 128, ((T) + 2) << 6,                                \
              smem + (P) * 65536 + 128 * 128);                                \
    }                                                                         \
    __builtin_amdgcn_s_barrier();                                             \
    asm volatile("s_waitcnt lgkmcnt(0)" ::: "memory");                        \
    __builtin_amdgcn_sched_barrier(0);                                        \
    __builtin_amdgcn_s_setprio(1);                                            \
    mfma_quad<2>(acc, afA, bf);                                               \
    __builtin_amdgcn_s_setprio(0);                                            \
    __builtin_amdgcn_s_barrier();                                             \
    /* -- q=3: no ds reads (frags prefetched at q=2) -- */                    \
    if ((T) + 2 < 64) {                                                       \
      stage64(A, blockM + 64,  ((T) + 2) << 6,                                \
              smem + (P) * 65536 + 64 * 128);                                 \
      stage64(A, blockM + 192, ((T) + 2) << 6,                                \
              smem + (P) * 65536 + 192 * 128);                                \
    }                                                                         \
    __builtin_amdgcn_s_barrier();                                             \
    __builtin_amdgcn_s_setprio(1);                                            \
    mfma_quad<3>(acc, afB, bf);                                               \
    __builtin_amdgcn_s_setprio(0);                                            \
    if ((T) < 62) {                                                           \
      asm volatile("s_waitcnt vmcnt(6)" ::: "memory");                        \
      __builtin_amdgcn_s_barrier();                                           \
    } else if ((T) == 62) {                                                   \
      asm volatile("s_waitcnt vmcnt(0)" ::: "memory");                        \
      __builtin_amdgcn_s_barrier();                                           \
    }                                                                         \
  }

__global__ __launch_bounds__(512, 2) void gemm_kernel(
    const unsigned short* __restrict__ A,
    const unsigned short* __restrict__ B,
    const float* __restrict__ bias,
    const double* __restrict__ sum,
    float* __restrict__ C) {
  __shared__ __align__(16) char smem[131072];  // buf p: A at p*64K, B at +32K

  const int tid = threadIdx.x;
  const int l = tid & 63;
  const int wid = tid >> 6;
  const int wm = wid >> 2;   // 0..1
  const int wn = wid & 3;    // 0..3

  // Bijective XCD swizzle: 1024 blocks, 8 XCDs; each XCD gets contiguous
  // logical chunk (16 consecutive tiles share one 2 MB A-panel -> L2-hit).
  const int lin = blockIdx.x;
  const int swz = ((lin & 7) << 7) | (lin >> 3);
  const int blockM = (swz >> 4) << 8;   // 0..16128
  const int blockN = (swz & 15) << 8;   // 0..3840

  // Per-lane LDS read offsets (16B units; swizzled chunk = cg ^ (row&7)).
  const int laneRow = l & 15;
  const int c0 = (l >> 4) ^ (l & 7);
  const int aOff0 = ((wm * 128 + laneRow) * 8 + c0) << 4;
  const int aOff1 = aOff0 ^ 64;   // kk=1: global chunk +4 -> byte bit6 toggles
  const int bOff0 = ((wn * 64 + laneRow) * 8 + c0) << 4;
  const int bOff1 = bOff0 ^ 64;

  floatx4 acc[8][4] = {};
  short8 bf[4][2], afA[2][2], afB[2][2];

  // Prologue: tile0 {A0,A1,B0,B1} + tile1 {B0,A0,A1} = 14 loads/thread;
  // vmcnt(6) -> tile0's 8 loads landed, tile1's 6 in flight.
  stage64(A, blockM + 0,   0, smem + 0);
  stage64(A, blockM + 128, 0, smem + 128 * 128);
  stage64(A, blockM + 64,  0, smem + 64 * 128);
  stage64(A, blockM + 192, 0, smem + 192 * 128);
  stage64(B, blockN + 0,   0, smem + 32768);
  stage64(B, blockN + 64,  0, smem + 32768 + 64 * 128);
  stage64(B, blockN + 128, 0, smem + 32768 + 128 * 128);
  stage64(B, blockN + 192, 0, smem + 32768 + 192 * 128);
  stage64(B, blockN + 0,   64, smem + 65536 + 32768);
  stage64(B, blockN + 64,  64, smem + 65536 + 32768 + 64 * 128);
  stage64(A, blockM + 0,   64, smem + 65536);
  stage64(A, blockM + 128, 64, smem + 65536 + 128 * 128);
  stage64(A, blockM + 64,  64, smem + 65536 + 64 * 128);
  stage64(A, blockM + 192, 64, smem + 65536 + 192 * 128);
  asm volatile("s_waitcnt vmcnt(6)" ::: "memory");
  __builtin_amdgcn_s_barrier();

  for (int tp = 0; tp < 32; ++tp) {
    const int t0 = tp * 2;
    TILE_BODY(t0, 0)
    TILE_BODY(t0 + 1, 1)
  }

  // Epilogue: C = acc*scale + bias. C/D layout: col=l&15, row=(l>>4)*4+reg.
  const float s = get_scale(sum);
  const int col16 = l & 15;
  const int rquad = (l >> 4) * 4;
#pragma unroll
  for (int ni = 0; ni < 4; ++ni) {
    const int col = blockN + wn * 64 + ni * 16 + col16;
    const float bv = bias[col];
#pragma unroll
    for (int mi = 0; mi < 8; ++mi) {
      const int row0 = blockM + wm * 128 + mi * 16 + rquad;
      float* Cp = C + (size_t)row0 * N_DIM + col;
#pragma unroll
      for (int r = 0; r < 4; ++r)
        Cp[(size_t)r * N_DIM] = acc[mi][ni][r] * s + bv;
    }
  }
}

// ---------------------------------------------------------------------------
extern "C" void kernel_launch(void* const* d_in, const int* in_sizes, int n_in,
                              void* d_out, int out_size, void* d_ws, size_t ws_size,
                              hipStream_t stream) {
  const float* x = (const float*)d_in[0];     // [8,2048,4096] fp32
  const float* wt = (const float*)d_in[1];    // [4096,4096] fp32
  const float* bias = (const float*)d_in[2];  // [4096] fp32
  float* out = (float*)d_out;                 // [8,2048,4096] fp32

  if (ws_size < WS_NEEDED) return;

  double* sum = (double*)((char*)d_ws + WS_SUM_OFF);
  double* partials = (double*)((char*)d_ws + WS_PART_OFF);
  unsigned short* xb = (unsigned short*)((char*)d_ws + WS_X_OFF);
  unsigned short* wb = (unsigned short*)((char*)d_ws + WS_W_OFF);

  prep_kernel<<<4096, 256, 0, stream>>>(wt, partials, x, xb);
  reduce2_kernel<<<1, 256, 0, stream>>>(partials, sum);
  quantw_kernel<<<1024, 256, 0, stream>>>(wt, sum, wb);
  gemm_kernel<<<1024, 512, 0, stream>>>(xb, wb, bias, sum, out);
}